// Round 10
// baseline (345.912 us; speedup 1.0000x reference)
//
#include <hip/hip_runtime.h>
#include <hip/hip_bf16.h>
#include <cstdint>

typedef __bf16 bf16x8 __attribute__((ext_vector_type(8)));
typedef float floatx4 __attribute__((ext_vector_type(4)));

__device__ __forceinline__ void gl2lds16(const void* g, void* l) {
  __builtin_amdgcn_global_load_lds(
      (const __attribute__((address_space(1))) unsigned int*)g,
      (__attribute__((address_space(3))) unsigned int*)(uintptr_t)l,
      16, 0, 0);
}

// ---------------- fp32 -> bf16 convert ----------------
__global__ __launch_bounds__(256)
void cvt_kernel(const float* __restrict__ in, __hip_bfloat16* __restrict__ out, int n) {
  int i = (blockIdx.x * 256 + threadIdx.x) * 4;
  if (i >= n) return;
  const float4 v = *(const float4*)(in + i);
  out[i + 0] = __float2bfloat16(v.x);
  out[i + 1] = __float2bfloat16(v.y);
  out[i + 2] = __float2bfloat16(v.z);
  out[i + 3] = __float2bfloat16(v.w);
}

// fused cvt of x (n0 elems) and w_qkv into one contiguous bf16 output
__global__ __launch_bounds__(256)
void cvt2_kernel(const float* __restrict__ in0, const float* __restrict__ in1,
                 __hip_bfloat16* __restrict__ out, int n0, int ntot) {
  int i = (blockIdx.x * 256 + threadIdx.x) * 4;
  if (i >= ntot) return;
  const float4 v = (i < n0) ? *(const float4*)(in0 + i)
                            : *(const float4*)(in1 + (i - n0));
  out[i + 0] = __float2bfloat16(v.x);
  out[i + 1] = __float2bfloat16(v.y);
  out[i + 2] = __float2bfloat16(v.z);
  out[i + 3] = __float2bfloat16(v.w);
}

#define MEMFENCE asm volatile("" ::: "memory")

// ===== QKV GEMM: 256M x 128N tile, 2-buffer, 3 blocks/CU (m97-style overlap) ===
// 8 waves as 4M x 2N (per-wave 64x64, acc[4][4]). BK=32, depth-2 prefetch.
// Grid 768 = 256 CU x 3 blocks -> exactly ONE dispatch round.
// Per K-step: waitcnt vmcnt(3) [tile t landed; t+1 in flight] -> barrierA ->
// compute(t) -> barrierB [all waves' reads of buf t%2 done] -> stage(t+2) into
// buf t%2. Cross-block overlap (3/CU) hides the staging latency (m97: 912 TF).
// XOR granule swizzle (R2-validated). XCD-chunked bijective swizzle (768%8==0).
__global__ __launch_bounds__(512, 4)
void gemm_qkvB(const __hip_bfloat16* __restrict__ A,
               const __hip_bfloat16* __restrict__ W,
               __hip_bfloat16* __restrict__ Qr,
               __hip_bfloat16* __restrict__ Kr,
               __hip_bfloat16* __restrict__ Vt)
{
  extern __shared__ __hip_bfloat16 sm[];   // 49408 B: 2 bufs x 24KB + invf 256B
  const int tid = threadIdx.x, lane = tid & 63, wave = tid >> 6;
  const int wr = wave >> 1, wc = wave & 1;               // 4M x 2N
  const int idx = blockIdx.y * 16 + blockIdx.x;          // grid (16,48)
  const int swz = (idx & 7) * 96 + (idx >> 3);           // XCD chunk (768%8==0)
  const int m0 = (swz & 15) << 8;                        // 16 m-tiles of 256
  const int n0 = (swz >> 4) << 7;                        // 48 n-tiles of 128
  const int lrow = lane & 15, dg = lane >> 4, lq4 = dg * 4;
  const int rslot = (dg ^ ((lrow >> 1) & 3)) * 8;
  const int arow = tid >> 2;
  const int ascol = ((tid & 3) ^ ((tid >> 3) & 3)) * 8;
  const __hip_bfloat16* aS0 = A + (size_t)(m0 + arow) * 2048 + ascol;
  const __hip_bfloat16* aS1 = A + (size_t)(m0 + 128 + arow) * 2048 + ascol;
  const __hip_bfloat16* bS0 = W + (size_t)(n0 + arow) * 2048 + ascol;
  float* invfp = (float*)((char*)sm + 49152);
  if (tid < 64) invfp[tid] = __expf(-(float)tid * 0.14391156831212787f);
  floatx4 acc[4][4] = {};

#define BSTG(TT) do { const int bo_ = ((TT) & 1) * 12288; const int kk_ = (TT) * 32; \
    gl2lds16(aS0 + kk_, &sm[bo_ + tid * 8]);                                   \
    gl2lds16(aS1 + kk_, &sm[bo_ + 4096 + tid * 8]);                            \
    gl2lds16(bS0 + kk_, &sm[bo_ + 8192 + tid * 8]); } while (0)

#define BCOMP(BO) do {                                                         \
    bf16x8 af[4], bfr[4];                                                      \
    _Pragma("unroll")                                                          \
    for (int mt = 0; mt < 4; mt++)                                             \
      af[mt] = *(const bf16x8*)&sm[(BO) + (wr * 64 + mt * 16 + lrow) * 32 + rslot]; \
    _Pragma("unroll")                                                          \
    for (int nt = 0; nt < 4; nt++)                                             \
      bfr[nt] = *(const bf16x8*)&sm[(BO) + 8192 + (wc * 64 + nt * 16 + lrow) * 32 + rslot]; \
    __builtin_amdgcn_s_setprio(1);                                             \
    _Pragma("unroll")                                                          \
    for (int mt = 0; mt < 4; mt++)                                             \
      _Pragma("unroll")                                                        \
      for (int nt = 0; nt < 4; nt++)                                           \
        acc[mt][nt] = __builtin_amdgcn_mfma_f32_16x16x32_bf16(af[mt], bfr[nt], acc[mt][nt], 0, 0, 0); \
    __builtin_amdgcn_s_setprio(0);                                             \
  } while (0)

  BSTG(0); BSTG(1);   // 6 VMEM in flight
  // 0x0073 = vmcnt(3) lgkm(0); 0x0070 = vmcnt(0) lgkm(0)
  for (int t = 0; t < 63; ++t) {
    MEMFENCE; __builtin_amdgcn_s_waitcnt(0x0073); MEMFENCE;
    __builtin_amdgcn_s_barrier(); MEMFENCE;
    BCOMP((t & 1) * 12288);
    if (t <= 61) {
      MEMFENCE; __builtin_amdgcn_s_barrier(); MEMFENCE;
      BSTG(t + 2);
    }
  }
  MEMFENCE; __builtin_amdgcn_s_waitcnt(0x0070); MEMFENCE;
  __builtin_amdgcn_s_barrier(); MEMFENCE;
  BCOMP(12288);   // t = 63 -> buf 1
#undef BCOMP
#undef BSTG

  // -------- epilogue: n-tile = 1 head; 2-pass (rows 0-127, 128-255) --------
  const int seg = n0 >> 11;               // 0=Q 1=K 2=V
  const int h = (n0 & 2047) >> 7;
  const int b = m0 >> 11;
  const int seq0 = m0 & 2047;
  const float qs = (seg == 0) ? 0.08838834764831845f : 1.0f;
  for (int p = 0; p < 2; ++p) {
    __syncthreads();
    if ((wr >> 1) == p) {                 // waves {2p, 2p+1} own these 128 rows
      const int rb = (wr & 1) * 64;
      if (seg < 2) {                      // Csh[row 128][136]
#pragma unroll
        for (int mt = 0; mt < 4; mt++)
#pragma unroll
          for (int nt = 0; nt < 4; nt++)
#pragma unroll
            for (int r = 0; r < 4; r++)
              sm[(rb + mt * 16 + lq4 + r) * 136 + wc * 64 + nt * 16 + lrow] =
                  __float2bfloat16(acc[mt][nt][r]);
      } else {                            // CshT[col 128][136]
#pragma unroll
        for (int mt = 0; mt < 4; mt++)
#pragma unroll
          for (int nt = 0; nt < 4; nt++)
#pragma unroll
            for (int r = 0; r < 4; r++)
              sm[(wc * 64 + nt * 16 + lrow) * 136 + rb + mt * 16 + lq4 + r] =
                  __float2bfloat16(acc[mt][nt][r]);
      }
    }
    __syncthreads();
    if (seg < 2) {
      __hip_bfloat16* Out = seg ? Kr : Qr;
#pragma unroll
      for (int it = 0; it < 2; ++it) {
        const int task = tid + it * 512;  // 1024 tasks: 128 rows x 8 col-groups
        const int row = task >> 3;
        const int g8 = (task & 7) * 8;
        const int seq = seq0 + p * 128 + row;
        const float pos = (float)seq;
        const bf16x8 lo8 = *(const bf16x8*)&sm[row * 136 + g8];
        const bf16x8 hi8 = *(const bf16x8*)&sm[row * 136 + g8 + 64];
        alignas(16) __hip_bfloat16 lo[8], hi[8];
#pragma unroll
        for (int k = 0; k < 8; k++) {
          float sn, cs;
          __sincosf(pos * invfp[g8 + k], &sn, &cs);
          const float a = (float)lo8[k];
          const float bb2 = (float)hi8[k];
          lo[k] = __float2bfloat16((a * cs - bb2 * sn) * qs);
          hi[k] = __float2bfloat16((bb2 * cs + a * sn) * qs);
        }
        const size_t ob = ((size_t)((b * 16 + h) * 2048 + seq)) * 128;
        *(bf16x8*)&Out[ob + g8] = *(const bf16x8*)lo;
        *(bf16x8*)&Out[ob + g8 + 64] = *(const bf16x8*)hi;
      }
    } else {
#pragma unroll
      for (int it = 0; it < 4; ++it) {
        const int task = tid + it * 512;  // 2048 tasks: 128 d x 16 seq-groups
        const int col = task >> 4;
        const int sg = (task & 15) * 8;
        const bf16x8 v8 = *(const bf16x8*)&sm[col * 136 + sg];
        *(bf16x8*)&Vt[((size_t)((b * 16 + h) * 128 + col)) * 2048 + seq0 + p * 128 + sg] = v8;
      }
    }
  }
}

// ============ O-proj GEMM: 256M x 128N tile, grid 16x16 (R5, unchanged) ========
__global__ __launch_bounds__(512, 2)
void gemm_o256(const __hip_bfloat16* __restrict__ A,
               const __hip_bfloat16* __restrict__ Wo,
               float* __restrict__ C)
{
  extern __shared__ __hip_bfloat16 sm[];   // 96KB: 4 bufs x (A 8192 + B 4096)
  const int tid = threadIdx.x, lane = tid & 63, wave = tid >> 6;
  const int wr = wave >> 2, wc = wave & 3;
  const int m0 = blockIdx.x << 8, n0 = blockIdx.y << 7;
  const int lrow = lane & 15, dg = lane >> 4, lq4 = dg * 4;
  const int rslot = (dg ^ ((lrow >> 1) & 3)) * 8;
  const int arow = tid >> 2;
  const int ascol = ((tid & 3) ^ ((tid >> 3) & 3)) * 8;
  const __hip_bfloat16* aS0 = A + (size_t)(m0 + arow) * 2048 + ascol;
  const __hip_bfloat16* aS1 = A + (size_t)(m0 + 128 + arow) * 2048 + ascol;
  const __hip_bfloat16* bS0 = Wo + (size_t)(n0 + arow) * 2048 + ascol;
  floatx4 acc[8][2] = {};

#define OSTAGE(TT) do { const int bb_ = (TT) & 3; const int kk_ = (TT) * 32;   \
    gl2lds16(aS0 + kk_, &sm[bb_ * 12288 + tid * 8]);                           \
    gl2lds16(aS1 + kk_, &sm[bb_ * 12288 + 4096 + tid * 8]);                    \
    gl2lds16(bS0 + kk_, &sm[bb_ * 12288 + 8192 + tid * 8]); } while (0)

#define OKSTEP(TT, WIMM, DOSTAGE) do {                                         \
    MEMFENCE; __builtin_amdgcn_s_waitcnt(WIMM); MEMFENCE;                      \
    __builtin_amdgcn_s_barrier(); MEMFENCE;                                    \
    const int bb = (TT) & 3;                                                   \
    if (DOSTAGE) OSTAGE((TT) + 3);                                             \
    bf16x8 af[8], bfr[2];                                                      \
    _Pragma("unroll")                                                          \
    for (int mt = 0; mt < 8; mt++)                                             \
      af[mt] = *(const bf16x8*)&sm[bb * 12288 + (wr * 128 + mt * 16 + lrow) * 32 + rslot]; \
    _Pragma("unroll")                                                          \
    for (int nt = 0; nt < 2; nt++)                                             \
      bfr[nt] = *(const bf16x8*)&sm[bb * 12288 + 8192 + (wc * 32 + nt * 16 + lrow) * 32 + rslot]; \
    __builtin_amdgcn_s_setprio(1);                                             \
    _Pragma("unroll")                                                          \
    for (int mt = 0; mt < 8; mt++)                                             \
      _Pragma("unroll")                                                        \
      for (int nt = 0; nt < 2; nt++)                                           \
        acc[mt][nt] = __builtin_amdgcn_mfma_f32_16x16x32_bf16(af[mt], bfr[nt], acc[mt][nt], 0, 0, 0); \
    __builtin_amdgcn_s_setprio(0);                                             \
  } while (0)

  OSTAGE(0); OSTAGE(1); OSTAGE(2);   // 9 VMEM in flight
  // 0x0076=vmcnt(6)lgkm(0)  0x0073=vmcnt(3)  0x0070=vmcnt(0)
  for (int t = 0; t < 61; ++t) OKSTEP(t, 0x0076, true);
  OKSTEP(61, 0x0076, false);
  OKSTEP(62, 0x0073, false);
  OKSTEP(63, 0x0070, false);
#undef OKSTEP
#undef OSTAGE

#pragma unroll
  for (int mt = 0; mt < 8; mt++)
#pragma unroll
    for (int nt = 0; nt < 2; nt++)
#pragma unroll
      for (int r = 0; r < 4; r++)
        C[(size_t)(m0 + wr * 128 + mt * 16 + lq4 + r) * 2048 +
          (n0 + wc * 32 + nt * 16 + lrow)] = acc[mt][nt][r];
}

// ---------------- sliding-window flash attention (R5-exact) -------------------
#define KSTR 136
#define VSTR 72
__global__ __launch_bounds__(512, 4)
void attn_swa(const __hip_bfloat16* __restrict__ Qr, const __hip_bfloat16* __restrict__ Kr,
              const __hip_bfloat16* __restrict__ Vt, __hip_bfloat16* __restrict__ Out)
{
  __shared__ __hip_bfloat16 Ks[64 * KSTR];
  __shared__ __hip_bfloat16 Vs[128 * VSTR];
  __shared__ __hip_bfloat16 Pb[8][16 * VSTR];
  const int qt = blockIdx.x, bh = blockIdx.y;
  const int tid = threadIdx.x, lane = tid & 63, wave = tid >> 6;
  const int lrow = lane & 15, lk = (lane >> 4) * 8, lq4 = (lane >> 4) * 4;
  const int i0 = qt * 128;
  const float NEG_INF = -__builtin_inff();
  const __hip_bfloat16* Qh = Qr + (size_t)bh * 2048 * 128;
  const __hip_bfloat16* Kh = Kr + (size_t)bh * 2048 * 128;
  const __hip_bfloat16* Vh = Vt + (size_t)bh * 128 * 2048;

  const int ck0 = tid, ck1 = tid + 512;
  const int kr0 = ck0 >> 4, kg0 = (ck0 & 15) * 8;
  const int kr1 = ck1 >> 4, kg1 = (ck1 & 15) * 8;
  const int cv0 = tid, cv1 = tid + 512;
  const int vd0 = cv0 >> 3, vc0 = (cv0 & 7) * 8;
  const int vd1 = cv1 >> 3, vc1 = (cv1 & 7) * 8;

  const int iw = i0 + wave * 16 + lrow;
  bf16x8 qf[4];
#pragma unroll
  for (int ks = 0; ks < 4; ks++)
    qf[ks] = *(const bf16x8*)&Qh[(size_t)iw * 128 + ks * 32 + lk];

  floatx4 accO[8] = {};
  float m_i = NEG_INF, l_i = 0.f;
  const int imin = i0 + wave * 16;
  const int lo = i0 - 511;
  const int jt_lo = (lo > 0 ? lo : 0) >> 6;
  const int jt_hi = (i0 + 127) >> 6;

  int j0n = jt_lo * 64;
  int4 rk0 = *(const int4*)&Kh[(size_t)(j0n + kr0) * 128 + kg0];
  int4 rk1 = *(const int4*)&Kh[(size_t)(j0n + kr1) * 128 + kg1];
  int4 rv0 = *(const int4*)&Vh[(size_t)vd0 * 2048 + j0n + vc0];
  int4 rv1 = *(const int4*)&Vh[(size_t)vd1 * 2048 + j0n + vc1];

  for (int jt = jt_lo; jt <= jt_hi; jt++) {
    const int j0 = jt * 64;
    __syncthreads();
    *(int4*)&Ks[kr0 * KSTR + kg0] = rk0;
    *(int4*)&Ks[kr1 * KSTR + kg1] = rk1;
    *(int4*)&Vs[vd0 * VSTR + vc0] = rv0;
    *(int4*)&Vs[vd1 * VSTR + vc1] = rv1;
    if (jt < jt_hi) {
      const int jn = j0 + 64;
      rk0 = *(const int4*)&Kh[(size_t)(jn + kr0) * 128 + kg0];
      rk1 = *(const int4*)&Kh[(size_t)(jn + kr1) * 128 + kg1];
      rv0 = *(const int4*)&Vh[(size_t)vd0 * 2048 + jn + vc0];
      rv1 = *(const int4*)&Vh[(size_t)vd1 * 2048 + jn + vc1];
    }
    asm volatile("" ::: "memory");
    __builtin_amdgcn_s_waitcnt(0xC07F);
    __builtin_amdgcn_s_barrier();
    asm volatile("" ::: "memory");

    floatx4 s[4] = {};
#pragma unroll
    for (int nt = 0; nt < 4; nt++) {
      const int krow = (nt * 16 + lrow) * KSTR;
#pragma unroll
      for (int ks = 0; ks < 4; ks++) {
        const bf16x8 kf = *(const bf16x8*)&Ks[krow + ks * 32 + lk];
        s[nt] = __builtin_amdgcn_mfma_f32_16x16x32_bf16(kf, qf[ks], s[nt], 0, 0, 0);
      }
    }
    const bool full = (j0 + 63 <= imin) && (j0 >= imin + 15 - 511);
    float rmax = NEG_INF;
    if (full) {
#pragma unroll
      for (int nt = 0; nt < 4; nt++)
#pragma unroll
        for (int r = 0; r < 4; r++) rmax = fmaxf(rmax, s[nt][r]);
    } else {
#pragma unroll
      for (int nt = 0; nt < 4; nt++) {
#pragma unroll
        for (int r = 0; r < 4; r++) {
          const int j = j0 + nt * 16 + lq4 + r;
          const float sv = ((j <= iw) && (j > iw - 512)) ? s[nt][r] : NEG_INF;
          s[nt][r] = sv;
          rmax = fmaxf(rmax, sv);
        }
      }
    }
    rmax = fmaxf(rmax, __shfl_xor(rmax, 16));
    rmax = fmaxf(rmax, __shfl_xor(rmax, 32));
    const float mnew = fmaxf(m_i, rmax);
    const float alpha = __expf(fminf(m_i - mnew, 0.f));
    m_i = mnew;
    float rs = 0.f;
    if (full) {
#pragma unroll
      for (int nt = 0; nt < 4; nt++)
#pragma unroll
        for (int r = 0; r < 4; r++) {
          const float p = __expf(s[nt][r] - mnew);
          s[nt][r] = p;
          rs += p;
        }
    } else {
#pragma unroll
      for (int nt = 0; nt < 4; nt++)
#pragma unroll
        for (int r = 0; r < 4; r++) {
          const float sv = s[nt][r];
          const float p = (sv == NEG_INF) ? 0.f : __expf(sv - mnew);
          s[nt][r] = p;
          rs += p;
        }
    }
    rs += __shfl_xor(rs, 16);
    rs += __shfl_xor(rs, 32);
    l_i = l_i * alpha + rs;
#pragma unroll
    for (int dt = 0; dt < 8; dt++) accO[dt] *= alpha;
#pragma unroll
    for (int nt = 0; nt < 4; nt++) {
      alignas(8) __hip_bfloat16 p4[4];
#pragma unroll
      for (int r = 0; r < 4; r++) p4[r] = __float2bfloat16(s[nt][r]);
      *(uint64_t*)&Pb[wave][lrow * VSTR + nt * 16 + lq4] = *(const uint64_t*)p4;
    }
    bf16x8 pf[2];
#pragma unroll
    for (int jf = 0; jf < 2; jf++)
      pf[jf] = *(const bf16x8*)&Pb[wave][lrow * VSTR + jf * 32 + lk];
#pragma unroll
    for (int dt = 0; dt < 8; dt++) {
      const int vrow = (dt * 16 + lrow) * VSTR;
#pragma unroll
      for (int jf = 0; jf < 2; jf++) {
        const bf16x8 vf = *(const bf16x8*)&Vs[vrow + jf * 32 + lk];
        accO[dt] = __builtin_amdgcn_mfma_f32_16x16x32_bf16(vf, pf[jf], accO[dt], 0, 0, 0);
      }
    }
  }
  const int b = bh >> 4, h = bh & 15;
  const float inv_l = 1.0f / l_i;
  const size_t rowb = ((size_t)(b * 2048 + iw)) * 2048 + h * 128;
#pragma unroll
  for (int dt = 0; dt < 8; dt++) {
    alignas(8) __hip_bfloat16 o4[4];
#pragma unroll
    for (int r = 0; r < 4; r++) o4[r] = __float2bfloat16(accO[dt][r] * inv_l);
    *(uint64_t*)&Out[rowb + dt * 16 + lq4] = *(const uint64_t*)o4;
  }
}

// ---------------- launch ----------------
extern "C" void kernel_launch(void* const* d_in, const int* in_sizes, int n_in,
                              void* d_out, int out_size, void* d_ws, size_t ws_size,
                              hipStream_t stream)
{
  const float* x = (const float*)d_in[0];      // [2,2048,2048]
  const float* w_qkv = (const float*)d_in[1];  // [6144,2048]
  const float* w_o = (const float*)d_in[2];    // [2048,2048]
  float* y = (float*)d_out;                    // [2,2048,2048] fp32
  char* ws = (char*)d_ws;

  const size_t SZ_X = 16777216;     // 4096*2048*2 B
  const size_t SZ_WQKV = 25165824;  // 6144*2048*2 B
  const size_t SZ_Q = 16777216;     // 32*2048*128*2 B

  __hip_bfloat16* xb = (__hip_bfloat16*)(ws);            // x bf16; later attn out
  __hip_bfloat16* wqkvb = (__hip_bfloat16*)(ws + SZ_X);  // w_qkv bf16; later w_o bf16
  __hip_bfloat16* Qr = (__hip_bfloat16*)(ws + SZ_X + SZ_WQKV);
  __hip_bfloat16* Kr = (__hip_bfloat16*)(ws + SZ_X + SZ_WQKV + SZ_Q);
  __hip_bfloat16* Vt = (__hip_bfloat16*)(ws + SZ_X + SZ_WQKV + 2 * SZ_Q);

  static bool s_attr_done = false;
  if (!s_attr_done) {
    hipFuncSetAttribute((const void*)gemm_qkvB,
                        hipFuncAttributeMaxDynamicSharedMemorySize, 49408);
    hipFuncSetAttribute((const void*)gemm_o256,
                        hipFuncAttributeMaxDynamicSharedMemorySize, 98304);
    s_attr_done = true;
  }

  // x + w_qkv converted in one launch (outputs are contiguous in ws)
  cvt2_kernel<<<dim3(20480), dim3(256), 0, stream>>>(x, w_qkv, xb, 8388608, 20971520);
  gemm_qkvB<<<dim3(16, 48), dim3(512), 49408, stream>>>(xb, wqkvb, Qr, Kr, Vt);
  attn_swa<<<dim3(16, 32), dim3(512), 0, stream>>>(Qr, Kr, Vt, xb /*attn_out*/);
  cvt_kernel<<<dim3(4096), dim3(256), 0, stream>>>(w_o, wqkvb, 4194304);
  gemm_o256<<<dim3(16, 16), dim3(512), 98304, stream>>>(xb, wqkvb, y);
}